// Round 1
// baseline (280.401 us; speedup 1.0000x reference)
//
#include <hip/hip_runtime.h>
#include <cstdint>
#include <cmath>

#define D_MODEL 1024
#define SEQ 2048
#define BATCH 4

typedef short bf16x8 __attribute__((ext_vector_type(8)));
typedef float f32x4 __attribute__((ext_vector_type(4)));

__device__ __forceinline__ short f2bf(float f) {
  union { float f; unsigned int u; } v; v.f = f;
  unsigned int r = (v.u + 0x7FFFu + ((v.u >> 16) & 1u)) >> 16;
  return (short)r;
}

__device__ __forceinline__ float bf2f(short h) {
  union { unsigned int u; float f; } v;
  v.u = ((unsigned int)(unsigned short)h) << 16;
  return v.f;
}

__device__ __forceinline__ f32x4 mfma16(bf16x8 a, bf16x8 b, f32x4 c) {
  return __builtin_amdgcn_mfma_f32_16x16x32_bf16(a, b, c, 0, 0, 0);
}

__device__ __forceinline__ void load_lds16(const void* g, void* l) {
  __builtin_amdgcn_global_load_lds(
      (const __attribute__((address_space(1))) unsigned int*)g,
      (__attribute__((address_space(3))) unsigned int*)l, 16, 0, 0);
}

// ---------------- prep: x fp32 -> bf16 ----------------
__global__ __launch_bounds__(256) void convert_x(const float* __restrict__ x,
                                                 short* __restrict__ xb) {
  int i = blockIdx.x * 256 + threadIdx.x;
  float4 f = ((const float4*)x)[i];
  short4 h;
  h.x = f2bf(f.x); h.y = f2bf(f.y); h.z = f2bf(f.z); h.w = f2bf(f.w);
  ((short4*)xb)[i] = h;
}

// ---------------- prep: W [k][n] fp32 -> Wt [n][k] bf16 ----------------
__global__ __launch_bounds__(256) void transpose_w(const float* __restrict__ Wq,
                                                   const float* __restrict__ Wk,
                                                   const float* __restrict__ Wv,
                                                   short* __restrict__ wt) {
  const int mat = blockIdx.z;
  const float* __restrict__ W = (mat == 0) ? Wq : (mat == 1) ? Wk : Wv;
  short* __restrict__ o = wt + (size_t)mat * (D_MODEL * D_MODEL);
  __shared__ float tile[32][33];
  const int k0 = blockIdx.x * 32, n0 = blockIdx.y * 32;
  const int lx = threadIdx.x & 31, ly = threadIdx.x >> 5;
#pragma unroll
  for (int i = 0; i < 4; ++i) {
    int r = ly + i * 8;
    tile[r][lx] = W[(size_t)(k0 + r) * D_MODEL + n0 + lx];
  }
  __syncthreads();
#pragma unroll
  for (int i = 0; i < 4; ++i) {
    int r = ly + i * 8;
    o[(size_t)(n0 + r) * D_MODEL + k0 + lx] = f2bf(tile[lx][r]);
  }
}

// ------- QKV GEMM: combined M=8192, N=3072, K=1024 -------
// 256x256 tile, BK=64, 512 thr (8 waves, 2Mx4N), multi-phase counted-vmcnt
// schedule (T3+T4) + setprio (T5). LDS 128 KiB static, 1 block/CU.
// LDS chunk layout: pos p of row r holds global 16B chunk p ^ (r&7).
__global__ __launch_bounds__(512, 2) void qkv_gemm(
    const short* __restrict__ xb, const short* __restrict__ wt,
    const float* __restrict__ bq, const float* __restrict__ bk,
    const float* __restrict__ bv, short* __restrict__ qo,
    short* __restrict__ ko, short* __restrict__ vo) {
  const int m0 = blockIdx.x * 256;
  const int n0 = blockIdx.y * 256;   // global over 3072 (Wq|Wk|Wv rows)

  __shared__ short a_lds[2][256 * 64];  // 64 KB
  __shared__ short b_lds[2][256 * 64];  // 64 KB

  const int tid = threadIdx.x;
  const int wid = tid >> 6;        // 0..7
  const int lane = tid & 63;
  const int quad = lane >> 4;
  const int l16 = lane & 15;
  const int wr = wid >> 2;         // 0..1 -> wave m-offset wr*128
  const int wc = wid & 3;          // 0..3 -> wave n-offset wc*64
  const int sw8 = l16 & 7;
  const int p0 = (quad ^ sw8) * 16;        // byte off of ksub0 chunk
  const int p1 = ((4 + quad) ^ sw8) * 16;  // byte off of ksub1 chunk
  const int aro = (wr * 128 + l16) * 128;  // byte row base (A, frag i=0)
  const int bro = (wc * 64 + l16) * 128;   // byte row base (B, frag j=0)

  f32x4 acc[8][4] = {};

  // stage K-tile kt2 (64 wide) into buf: 8 global_load_lds / thread.
  // global src is pre-swizzled so linear LDS dest + swizzled read match.
  auto stage = [&](int kt2, int buf) {
    const int k0 = kt2 << 6;
    char* abase = (char*)a_lds + buf * 32768;
    char* bbase = (char*)b_lds + buf * 32768;
#pragma unroll
    for (int i = 0; i < 4; ++i) {
      const int c = (i << 9) + tid;     // chunk 0..2047
      const int row = c >> 3;
      const int g = (c & 7) ^ (row & 7);
      load_lds16(xb + (size_t)(m0 + row) * D_MODEL + k0 + (g << 3),
                 abase + c * 16);
      load_lds16(wt + (size_t)(n0 + row) * D_MODEL + k0 + (g << 3),
                 bbase + c * 16);
    }
  };

  // one K-tile: 4 phases x 16 MFMA, 24 ds_read_b128 total (frag reuse).
  auto ktile = [&](int kt, int buf) {
    const char* al = (const char*)a_lds + buf * 32768;
    const char* bl = (const char*)b_lds + buf * 32768;
    bf16x8 af[4][2], bfr[4][2];
    // ---- phase 0: read A rows 0..3 + B cols 0..1; MFMA (i0..3 x j0..1)
#pragma unroll
    for (int i = 0; i < 4; ++i) {
      af[i][0] = *(const bf16x8*)(al + aro + i * 2048 + p0);
      af[i][1] = *(const bf16x8*)(al + aro + i * 2048 + p1);
    }
#pragma unroll
    for (int j = 0; j < 2; ++j) {
      bfr[j][0] = *(const bf16x8*)(bl + bro + j * 2048 + p0);
      bfr[j][1] = *(const bf16x8*)(bl + bro + j * 2048 + p1);
    }
    __builtin_amdgcn_s_barrier();
    asm volatile("s_waitcnt lgkmcnt(0)" ::: "memory");
    __builtin_amdgcn_sched_barrier(0);
    __builtin_amdgcn_s_setprio(1);
#pragma unroll
    for (int i = 0; i < 4; ++i)
#pragma unroll
      for (int j = 0; j < 2; ++j) {
        acc[i][j] = mfma16(af[i][0], bfr[j][0], acc[i][j]);
        acc[i][j] = mfma16(af[i][1], bfr[j][1], acc[i][j]);
      }
    __builtin_amdgcn_s_setprio(0);
    __builtin_amdgcn_s_barrier();
    // ---- phase 1: read B cols 2..3; MFMA (i0..3 x j2..3)
#pragma unroll
    for (int j = 2; j < 4; ++j) {
      bfr[j][0] = *(const bf16x8*)(bl + bro + j * 2048 + p0);
      bfr[j][1] = *(const bf16x8*)(bl + bro + j * 2048 + p1);
    }
    __builtin_amdgcn_s_barrier();
    asm volatile("s_waitcnt lgkmcnt(0)" ::: "memory");
    __builtin_amdgcn_sched_barrier(0);
    __builtin_amdgcn_s_setprio(1);
#pragma unroll
    for (int i = 0; i < 4; ++i)
#pragma unroll
      for (int j = 2; j < 4; ++j) {
        acc[i][j] = mfma16(af[i][0], bfr[j][0], acc[i][j]);
        acc[i][j] = mfma16(af[i][1], bfr[j][1], acc[i][j]);
      }
    __builtin_amdgcn_s_setprio(0);
    __builtin_amdgcn_s_barrier();
    // ---- phase 2: read A rows 4..7; MFMA (i4..7 x j2..3)
#pragma unroll
    for (int i = 0; i < 4; ++i) {
      af[i][0] = *(const bf16x8*)(al + aro + (i + 4) * 2048 + p0);
      af[i][1] = *(const bf16x8*)(al + aro + (i + 4) * 2048 + p1);
    }
    __builtin_amdgcn_s_barrier();
    asm volatile("s_waitcnt lgkmcnt(0)" ::: "memory");
    __builtin_amdgcn_sched_barrier(0);
    __builtin_amdgcn_s_setprio(1);
#pragma unroll
    for (int i = 0; i < 4; ++i)
#pragma unroll
      for (int j = 2; j < 4; ++j) {
        acc[i + 4][j] = mfma16(af[i][0], bfr[j][0], acc[i + 4][j]);
        acc[i + 4][j] = mfma16(af[i][1], bfr[j][1], acc[i + 4][j]);
      }
    __builtin_amdgcn_s_setprio(0);
    __builtin_amdgcn_s_barrier();  // <- all waves done reading buf
    // ---- phase 3: issue stage(kt+2 -> buf) early, MFMA (i4..7 x j0..1),
    //      counted vmcnt (never 0 in steady state), barrier.
    if (kt + 2 < 16) stage(kt + 2, buf);
    __builtin_amdgcn_s_setprio(1);
#pragma unroll
    for (int i = 0; i < 4; ++i)
#pragma unroll
      for (int j = 0; j < 2; ++j) {
        acc[i + 4][j] = mfma16(af[i][0], bfr[j][0], acc[i + 4][j]);
        acc[i + 4][j] = mfma16(af[i][1], bfr[j][1], acc[i + 4][j]);
      }
    __builtin_amdgcn_s_setprio(0);
    if (kt + 2 < 16)
      asm volatile("s_waitcnt vmcnt(8)" ::: "memory");  // kt+1's loads landed
    else
      asm volatile("s_waitcnt vmcnt(0)" ::: "memory");  // epilogue drain
    __builtin_amdgcn_s_barrier();
  };

  stage(0, 0);
  stage(1, 1);
  asm volatile("s_waitcnt vmcnt(8)" ::: "memory");  // buf0 ready
  __syncthreads();
  for (int kt = 0; kt < 16; kt += 2) {
    ktile(kt, 0);
    ktile(kt + 1, 1);
  }

  // epilogue: bias + bf16 store; block spans exactly one of Q/K/V.
  const int mat = n0 >> 10;
  const float* __restrict__ bias = (mat == 0) ? bq : (mat == 1) ? bk : bv;
  short* __restrict__ qko = (mat == 0) ? qo : ko;
  const int nbase = (n0 & 1023) + wc * 64;
#pragma unroll
  for (int i = 0; i < 8; ++i) {
#pragma unroll
    for (int j = 0; j < 4; ++j) {
#pragma unroll
      for (int r = 0; r < 4; ++r) {
        const int mrow = m0 + wr * 128 + i * 16 + quad * 4 + r;
        const int ncol = nbase + j * 16 + l16;
        const float val = acc[i][j][r] + bias[ncol];
        const short h = f2bf(val);
        if (mat == 2) {
          vo[((size_t)(mrow >> 11) * D_MODEL + ncol) * SEQ + (mrow & 2047)] = h;
        } else {
          qko[(size_t)mrow * D_MODEL + ncol] = h;
        }
      }
    }
  }
}

// ---------------- S = scale * Q K^T, causal tiles, dbuf + swizzle ----------------
__global__ __launch_bounds__(256) void sgemm(const short* __restrict__ qb,
                                             const short* __restrict__ kb,
                                             short* __restrict__ S) {
  if (blockIdx.y > blockIdx.x) return;
  const int m0 = blockIdx.x * 128;
  const int n0 = blockIdx.y * 128;
  const int b = blockIdx.z;
  const short* __restrict__ qp = qb + (size_t)b * SEQ * D_MODEL;
  const short* __restrict__ kp = kb + (size_t)b * SEQ * D_MODEL;

  __shared__ short a_lds[2][128 * 64];
  __shared__ short b_lds[2][128 * 64];

  const int tid = threadIdx.x;
  const int wid = tid >> 6;
  const int lane = tid & 63;
  const int quad = lane >> 4;
  const int l16 = lane & 15;
  const int mw = (wid >> 1) * 64;
  const int nw = (wid & 1) * 64;
  const int sw = l16 & 7;
  const int r_local = wid * 8 + (lane >> 3);
  const int c_sw = ((lane & 7) ^ (lane >> 3)) * 8;

  f32x4 acc[4][4] = {};

  auto stage = [&](int k0, int buf) {
#pragma unroll
    for (int it = 0; it < 4; ++it) {
      load_lds16(qp + (size_t)(m0 + it * 32 + r_local) * D_MODEL + k0 + c_sw,
                 (char*)a_lds[buf] + it * 4096 + wid * 1024);
      load_lds16(kp + (size_t)(n0 + it * 32 + r_local) * D_MODEL + k0 + c_sw,
                 (char*)b_lds[buf] + it * 4096 + wid * 1024);
    }
  };

  stage(0, 0);
  for (int k0 = 0; k0 < D_MODEL; k0 += 64) {
    const int buf = (k0 >> 6) & 1;
    __syncthreads();
    if (k0 + 64 < D_MODEL) stage(k0 + 64, buf ^ 1);
    const short* al = a_lds[buf];
    const short* bl = b_lds[buf];
#pragma unroll
    for (int kt = 0; kt < 2; ++kt) {
      bf16x8 af[4], bfr[4];
#pragma unroll
      for (int i = 0; i < 4; ++i)
        af[i] = *(const bf16x8*)(al + (mw + i * 16 + l16) * 64 +
                                 ((kt * 4 + quad) ^ sw) * 8);
#pragma unroll
      for (int i = 0; i < 4; ++i)
        bfr[i] = *(const bf16x8*)(bl + (nw + i * 16 + l16) * 64 +
                                  ((kt * 4 + quad) ^ sw) * 8);
#pragma unroll
      for (int i = 0; i < 4; ++i)
#pragma unroll
        for (int j = 0; j < 4; ++j)
          acc[i][j] = mfma16(af[i], bfr[j], acc[i][j]);
    }
  }
#pragma unroll
  for (int i = 0; i < 4; ++i) {
#pragma unroll
    for (int j = 0; j < 4; ++j) {
#pragma unroll
      for (int r = 0; r < 4; ++r) {
        const int mrow = m0 + mw + i * 16 + quad * 4 + r;
        const int ncol = n0 + nw + j * 16 + l16;
        S[((size_t)b * SEQ + mrow) * SEQ + ncol] = f2bf(acc[i][j][r] * 0.03125f);
      }
    }
  }
}

// ---------------- row softmax: S bf16 -> P bf16 (normalized, zero-padded) --------
__global__ __launch_bounds__(256) void softmax_rows(const short* __restrict__ S,
                                                    short* __restrict__ P) {
  const int row = blockIdx.x;          // 0..8191
  const int t = row & (SEQ - 1);
  const int tid = threadIdx.x;
  const short* __restrict__ srow = S + (size_t)row * SEQ;
  short* __restrict__ prow = P + (size_t)row * SEQ;

  __shared__ float red[4];

  float v[8];
#pragma unroll
  for (int i = 0; i < 8; ++i) {
    const int c = tid + i * 256;
    v[i] = (c <= t) ? bf2f(srow[c]) : -1e30f;
  }
  float m = v[0];
#pragma unroll
  for (int i = 1; i < 8; ++i) m = fmaxf(m, v[i]);
#pragma unroll
  for (int o = 32; o; o >>= 1) m = fmaxf(m, __shfl_xor(m, o));
  if ((tid & 63) == 0) red[tid >> 6] = m;
  __syncthreads();
  m = fmaxf(fmaxf(red[0], red[1]), fmaxf(red[2], red[3]));

  float e[8];
  float s = 0.f;
#pragma unroll
  for (int i = 0; i < 8; ++i) {
    e[i] = __expf(v[i] - m);   // -1e30 - m underflows to 0
    s += e[i];
  }
#pragma unroll
  for (int o = 32; o; o >>= 1) s += __shfl_xor(s, o);
  __syncthreads();
  if ((tid & 63) == 0) red[tid >> 6] = s;
  __syncthreads();
  s = red[0] + red[1] + red[2] + red[3];
  const float rinv = 1.0f / s;
  const int nwr = (t >> 8) + 1;   // chunks to write: covers pvgemm read extent
#pragma unroll
  for (int i = 0; i < 8; ++i)
    if (i < nwr) prow[tid + i * 256] = f2bf(e[i] * rinv);
}

// ---------------- O = P V (B = V^T layout), causal K, dbuf + swizzle -------------
// grid (8,4,16): x=d tile, y=batch, z: m0=(15-z)*128 (LPT: longest-K first).
__global__ __launch_bounds__(256) void pvgemm(const short* __restrict__ P,
                                              const short* __restrict__ vtb,
                                              float* __restrict__ out) {
  const int n0 = blockIdx.x * 128;
  const int b = blockIdx.y;
  const int m0 = (15 - blockIdx.z) * 128;
  const short* __restrict__ pp = P + (size_t)b * SEQ * SEQ;
  const short* __restrict__ vp = vtb + (size_t)b * D_MODEL * SEQ;
  const int kmax = m0 + 128;

  __shared__ short a_lds[2][128 * 64];
  __shared__ short b_lds[2][128 * 64];

  const int tid = threadIdx.x;
  const int wid = tid >> 6;
  const int lane = tid & 63;
  const int quad = lane >> 4;
  const int l16 = lane & 15;
  const int mw = (wid >> 1) * 64;
  const int nw = (wid & 1) * 64;
  const int sw = l16 & 7;
  const int r_local = wid * 8 + (lane >> 3);
  const int c_sw = ((lane & 7) ^ (lane >> 3)) * 8;

  f32x4 acc[4][4] = {};

  auto stage = [&](int k0, int buf) {
#pragma unroll
    for (int it = 0; it < 4; ++it) {
      load_lds16(pp + (size_t)(m0 + it * 32 + r_local) * SEQ + k0 + c_sw,
                 (char*)a_lds[buf] + it * 4096 + wid * 1024);
      load_lds16(vp + (size_t)(n0 + it * 32 + r_local) * SEQ + k0 + c_sw,
                 (char*)b_lds[buf] + it * 4096 + wid * 1024);
    }
  };

  stage(0, 0);
  for (int k0 = 0; k0 < kmax; k0 += 64) {
    const int buf = (k0 >> 6) & 1;
    __syncthreads();
    if (k0 + 64 < kmax) stage(k0 + 64, buf ^ 1);
    const short* al = a_lds[buf];
    const short* bl = b_lds[buf];
#pragma unroll
    for (int kt = 0; kt < 2; ++kt) {
      bf16x8 af[4], bfr[4];
#pragma unroll
      for (int i = 0; i < 4; ++i)
        af[i] = *(const bf16x8*)(al + (mw + i * 16 + l16) * 64 +
                                 ((kt * 4 + quad) ^ sw) * 8);
#pragma unroll
      for (int i = 0; i < 4; ++i)
        bfr[i] = *(const bf16x8*)(bl + (nw + i * 16 + l16) * 64 +
                                  ((kt * 4 + quad) ^ sw) * 8);
#pragma unroll
      for (int i = 0; i < 4; ++i)
#pragma unroll
        for (int j = 0; j < 4; ++j)
          acc[i][j] = mfma16(af[i], bfr[j], acc[i][j]);
    }
  }
#pragma unroll
  for (int i = 0; i < 4; ++i) {
#pragma unroll
    for (int j = 0; j < 4; ++j) {
#pragma unroll
      for (int r = 0; r < 4; ++r) {
        const int mrow = m0 + mw + i * 16 + quad * 4 + r;
        const int ncol = n0 + nw + j * 16 + l16;
        out[((size_t)b * SEQ + mrow) * D_MODEL + ncol] = acc[i][j][r];
      }
    }
  }
}

extern "C" void kernel_launch(void* const* d_in, const int* in_sizes, int n_in,
                              void* d_out, int out_size, void* d_ws, size_t ws_size,
                              hipStream_t stream) {
  (void)in_sizes; (void)n_in; (void)out_size; (void)ws_size;
  const float* x  = (const float*)d_in[0];
  const float* Wq = (const float*)d_in[1];
  const float* bq = (const float*)d_in[2];
  const float* Wk = (const float*)d_in[3];
  const float* bk = (const float*)d_in[4];
  const float* Wv = (const float*)d_in[5];
  const float* bv = (const float*)d_in[6];
  float* out = (float*)d_out;

  char* ws = (char*)d_ws;
  short* xb = (short*)(ws);                 // 16 MB   [dead after qkv_gemm]
  short* wt = (short*)(ws + 16777216);      // 6 MB    [dead after qkv_gemm]
  short* qo = (short*)(ws + 23068672);      // 16 MB   [dead after sgemm]
  short* ko = (short*)(ws + 39845888);      // 16 MB   [dead after sgemm]
  short* vo = (short*)(ws + 56623104);      // 16 MB   transposed [b][d][s]
  short* S  = (short*)(ws + 73400320);      // 32 MB bf16 [b][t][s]
  short* P  = (short*)(ws);                 // 32 MB, aliases xb/wt/qo (dead by then)

  convert_x<<<dim3(8192), dim3(256), 0, stream>>>(x, xb);
  transpose_w<<<dim3(32, 32, 3), dim3(256), 0, stream>>>(Wq, Wk, Wv, wt);
  qkv_gemm<<<dim3(32, 12), dim3(512), 0, stream>>>(xb, wt, bq, bk, bv, qo, ko, vo);
  sgemm<<<dim3(16, 16, BATCH), dim3(256), 0, stream>>>(qo, ko, S);
  softmax_rows<<<dim3(BATCH * SEQ), dim3(256), 0, stream>>>(S, P);
  pvgemm<<<dim3(8, BATCH, 16), dim3(256), 0, stream>>>(P, vo, out);
}